// Round 1
// baseline (399.392 us; speedup 1.0000x reference)
//
#include <hip/hip_runtime.h>

// ExtractGraph: maxpool(2x2) -> threshold=(max-min)/96 -> d=pool+noise ->
// diagonal-neighbor adjacency (|diff|<=thr), symmetric -> & dropout_mask ->
// row-major COO edge list padded with sentinel NUM_NODES.
//
// Single-workgroup fused kernel: the whole problem is ~36K candidate edges.
// d[] (9216 f32 = 36KB) lives in LDS; per-thread 9 nodes; block scan gives
// exact jnp.nonzero ordering. Mask (340MB) is only gathered where the
// threshold test passes (~4% of 36K candidates).

#define HW 192
#define MM 96
#define NUM_NODES 9216
#define MAX_EDGES 36864
#define NT 1024
#define NPT 9   // nodes per thread: 9216 / 1024

__global__ __launch_bounds__(NT) void extract_graph_kernel(
    const float* __restrict__ d_coarse,   // [192*192]
    const float* __restrict__ noise,      // [96*96]
    const int*   __restrict__ mask,       // [9216*9216] bool-as-int32
    int*         __restrict__ out)        // [2*36864] int32
{
    __shared__ float d_lds[NUM_NODES];
    __shared__ float redf[NT];
    __shared__ int   sc[NT];
    __shared__ float s_thr;

    const int t = threadIdx.x;

    // ---- Phase 1: 2x2 maxpool + noise into LDS; track pool min/max ----
    float vmax = -3.0e38f, vmin = 3.0e38f;
    #pragma unroll
    for (int k = 0; k < NPT; ++k) {
        int l = k * NT + t;
        int i = l / MM;
        int j = l - i * MM;
        const float* r0 = d_coarse + (2 * i) * HW + 2 * j;
        float a = r0[0], b = r0[1], c = r0[HW], e = r0[HW + 1];
        float p = fmaxf(fmaxf(a, b), fmaxf(c, e));
        vmax = fmaxf(vmax, p);
        vmin = fminf(vmin, p);
        d_lds[l] = p + noise[l];
    }

    // ---- Phase 2: block reduce max then min; threshold = (max-min)/96 ----
    redf[t] = vmax;
    __syncthreads();
    for (int s = NT / 2; s > 0; s >>= 1) {
        if (t < s) redf[t] = fmaxf(redf[t], redf[t + s]);
        __syncthreads();
    }
    float gmax = redf[0];
    __syncthreads();
    redf[t] = vmin;
    __syncthreads();
    for (int s = NT / 2; s > 0; s >>= 1) {
        if (t < s) redf[t] = fminf(redf[t], redf[t + s]);
        __syncthreads();
    }
    if (t == 0) s_thr = (gmax - redf[0]) / 96.0f;
    __syncthreads();
    const float thr = s_thr;

    // ---- Phase 3: per-node neighbor flags (ascending col order) ----
    // neighbors of l=(i,j): l-97, l-95, l+95, l+97
    int flags[NPT];
    int cnt = 0;
    #pragma unroll
    for (int n = 0; n < NPT; ++n) {
        int l = t * NPT + n;
        int i = l / MM;
        int j = l - i * MM;
        float dl = d_lds[l];
        int f = 0;
        const size_t rowbase = (size_t)l * NUM_NODES;
        if (i > 0) {
            if (j > 0 && fabsf(d_lds[l - 97] - dl) <= thr &&
                mask[rowbase + (l - 97)] != 0) f |= 1;
            if (j < MM - 1 && fabsf(d_lds[l - 95] - dl) <= thr &&
                mask[rowbase + (l - 95)] != 0) f |= 2;
        }
        if (i < MM - 1) {
            if (j > 0 && fabsf(d_lds[l + 95] - dl) <= thr &&
                mask[rowbase + (l + 95)] != 0) f |= 4;
            if (j < MM - 1 && fabsf(d_lds[l + 97] - dl) <= thr &&
                mask[rowbase + (l + 97)] != 0) f |= 8;
        }
        flags[n] = f;
        cnt += __popc(f);
    }

    // ---- Phase 4: block-wide exclusive scan of per-thread counts ----
    sc[t] = cnt;
    __syncthreads();
    for (int off = 1; off < NT; off <<= 1) {
        int v = sc[t] + ((t >= off) ? sc[t - off] : 0);
        __syncthreads();
        sc[t] = v;
        __syncthreads();
    }
    int pos = sc[t] - cnt;          // exclusive prefix
    const int total = sc[NT - 1];   // total edge count

    // ---- Phase 5: write compacted edges in row-major order ----
    #pragma unroll
    for (int n = 0; n < NPT; ++n) {
        int l = t * NPT + n;
        int f = flags[n];
        if (f & 1) { out[pos] = l; out[MAX_EDGES + pos] = l - 97; ++pos; }
        if (f & 2) { out[pos] = l; out[MAX_EDGES + pos] = l - 95; ++pos; }
        if (f & 4) { out[pos] = l; out[MAX_EDGES + pos] = l + 95; ++pos; }
        if (f & 8) { out[pos] = l; out[MAX_EDGES + pos] = l + 97; ++pos; }
    }

    // ---- Phase 6: sentinel-fill the tail ----
    for (int idx = total + t; idx < MAX_EDGES; idx += NT) {
        out[idx] = NUM_NODES;
        out[MAX_EDGES + idx] = NUM_NODES;
    }
}

extern "C" void kernel_launch(void* const* d_in, const int* in_sizes, int n_in,
                              void* d_out, int out_size, void* d_ws, size_t ws_size,
                              hipStream_t stream) {
    const float* d_coarse = (const float*)d_in[0];
    const float* noise    = (const float*)d_in[1];
    const int*   mask     = (const int*)d_in[2];
    // d_in[3] = R_scale (unused by the reference output)
    int* out = (int*)d_out;

    extract_graph_kernel<<<1, NT, 0, stream>>>(d_coarse, noise, mask, out);
}

// Round 2
// 376.175 us; speedup vs baseline: 1.0617x; 1.0617x over previous
//
#include <hip/hip_runtime.h>

// ExtractGraph: maxpool(2x2) -> threshold=(max-min)/96 -> d=pool+noise ->
// diagonal-neighbor adjacency (|diff|<=thr), symmetric -> & dropout_mask ->
// row-major COO edge list padded with sentinel NUM_NODES.
//
// R2: 3-kernel pipeline, 36 blocks x 256 threads (one thread per node).
// Cross-block deps (global min/max, global prefix) resolved by stream
// ordering between kernels instead of a single-CU mega-kernel. Mask (340MB)
// is only gathered where the threshold test passes (~5% of 36K candidates),
// now with 36 CUs of latency hiding instead of 1.

#define HW 192
#define MM 96
#define NUM_NODES 9216
#define MAX_EDGES 36864
#define NB 36
#define BT 256

// ws layout (4-byte words):
//   [0,     9216)  d_buf   (float)  pooled + noise
//   [9216,  9252)  blk_max (float)  per-block pool max
//   [9252,  9288)  blk_min (float)  per-block pool min
//   [9288, 18504)  flags   (int)    per-node 4-bit neighbor flags
//   [18504,18540)  blk_cnt (int)    per-block edge counts

__global__ __launch_bounds__(BT) void k_pool(
    const float* __restrict__ dc,
    const float* __restrict__ noise,
    float* __restrict__ d_buf,
    float* __restrict__ blk_max,
    float* __restrict__ blk_min)
{
    const int t = threadIdx.x;
    const int l = blockIdx.x * BT + t;
    const int i = l / MM, j = l - i * MM;
    const float* r0 = dc + (2 * i) * HW + 2 * j;
    float2 a = *(const float2*)r0;
    float2 b = *(const float2*)(r0 + HW);
    float p = fmaxf(fmaxf(a.x, a.y), fmaxf(b.x, b.y));
    d_buf[l] = p + noise[l];   // noise added AFTER threshold stats (on p)

    float mx = p, mn = p;
    #pragma unroll
    for (int off = 32; off > 0; off >>= 1) {
        mx = fmaxf(mx, __shfl_down(mx, off, 64));
        mn = fminf(mn, __shfl_down(mn, off, 64));
    }
    __shared__ float smx[4], smn[4];
    const int lane = t & 63, wid = t >> 6;
    if (lane == 0) { smx[wid] = mx; smn[wid] = mn; }
    __syncthreads();
    if (t == 0) {
        blk_max[blockIdx.x] = fmaxf(fmaxf(smx[0], smx[1]), fmaxf(smx[2], smx[3]));
        blk_min[blockIdx.x] = fminf(fminf(smn[0], smn[1]), fminf(smn[2], smn[3]));
    }
}

__global__ __launch_bounds__(BT) void k_flags(
    const float* __restrict__ d_buf,
    const float* __restrict__ blk_max,
    const float* __restrict__ blk_min,
    const int*   __restrict__ mask,
    int* __restrict__ flags,
    int* __restrict__ blk_cnt)
{
    __shared__ float s_thr;
    const int t = threadIdx.x;
    if (t < 64) {
        float mx = (t < NB) ? blk_max[t] : -3.0e38f;
        float mn = (t < NB) ? blk_min[t] :  3.0e38f;
        #pragma unroll
        for (int off = 32; off > 0; off >>= 1) {
            mx = fmaxf(mx, __shfl_down(mx, off, 64));
            mn = fminf(mn, __shfl_down(mn, off, 64));
        }
        if (t == 0) s_thr = (mx - mn) / 96.0f;
    }
    __syncthreads();
    const float thr = s_thr;

    const int l = blockIdx.x * BT + t;
    const int i = l / MM, j = l - i * MM;
    const float dl = d_buf[l];
    const size_t rowbase = (size_t)l * NUM_NODES;
    int f = 0;
    if (i > 0) {
        if (j > 0      && fabsf(d_buf[l - 97] - dl) <= thr && mask[rowbase + (l - 97)]) f |= 1;
        if (j < MM - 1 && fabsf(d_buf[l - 95] - dl) <= thr && mask[rowbase + (l - 95)]) f |= 2;
    }
    if (i < MM - 1) {
        if (j > 0      && fabsf(d_buf[l + 95] - dl) <= thr && mask[rowbase + (l + 95)]) f |= 4;
        if (j < MM - 1 && fabsf(d_buf[l + 97] - dl) <= thr && mask[rowbase + (l + 97)]) f |= 8;
    }
    flags[l] = f;

    int c = __popc(f);
    #pragma unroll
    for (int off = 32; off > 0; off >>= 1) c += __shfl_down(c, off, 64);
    __shared__ int sc[4];
    const int lane = t & 63, wid = t >> 6;
    if (lane == 0) sc[wid] = c;
    __syncthreads();
    if (t == 0) blk_cnt[blockIdx.x] = sc[0] + sc[1] + sc[2] + sc[3];
}

__global__ __launch_bounds__(BT) void k_write(
    const int* __restrict__ flags,
    const int* __restrict__ blk_cnt,
    int* __restrict__ out)
{
    const int t = threadIdx.x, b = blockIdx.x;

    // 36-entry prefix: every thread reads all block counts (L2-cached).
    int blkoff = 0, total = 0;
    #pragma unroll
    for (int k = 0; k < NB; ++k) {
        int c = blk_cnt[k];
        if (k < b) blkoff += c;
        total += c;
    }

    const int l = b * BT + t;
    const int f = flags[l];
    const int c = __popc(f);

    // inclusive wave scan, then cross-wave offsets via LDS
    int inc = c;
    const int lane = t & 63, wid = t >> 6;
    #pragma unroll
    for (int off = 1; off < 64; off <<= 1) {
        int v = __shfl_up(inc, off, 64);
        if (lane >= off) inc += v;
    }
    __shared__ int wtot[4];
    if (lane == 63) wtot[wid] = inc;
    __syncthreads();
    int wpre = 0;
    for (int k = 0; k < wid; ++k) wpre += wtot[k];

    int pos = blkoff + wpre + (inc - c);   // global exclusive prefix
    if (f & 1) { out[pos] = l; out[MAX_EDGES + pos] = l - 97; ++pos; }
    if (f & 2) { out[pos] = l; out[MAX_EDGES + pos] = l - 95; ++pos; }
    if (f & 4) { out[pos] = l; out[MAX_EDGES + pos] = l + 95; ++pos; }
    if (f & 8) { out[pos] = l; out[MAX_EDGES + pos] = l + 97; ++pos; }

    // sentinel tail, grid-strided across all 9216 threads
    for (int idx = total + b * BT + t; idx < MAX_EDGES; idx += NUM_NODES) {
        out[idx] = NUM_NODES;
        out[MAX_EDGES + idx] = NUM_NODES;
    }
}

extern "C" void kernel_launch(void* const* d_in, const int* in_sizes, int n_in,
                              void* d_out, int out_size, void* d_ws, size_t ws_size,
                              hipStream_t stream) {
    const float* d_coarse = (const float*)d_in[0];
    const float* noise    = (const float*)d_in[1];
    const int*   mask     = (const int*)d_in[2];
    int* out = (int*)d_out;

    float* ws      = (float*)d_ws;
    float* d_buf   = ws;
    float* blk_max = ws + 9216;
    float* blk_min = ws + 9252;
    int*   flags   = (int*)(ws + 9288);
    int*   blk_cnt = (int*)(ws + 18504);

    k_pool <<<NB, BT, 0, stream>>>(d_coarse, noise, d_buf, blk_max, blk_min);
    k_flags<<<NB, BT, 0, stream>>>(d_buf, blk_max, blk_min, mask, flags, blk_cnt);
    k_write<<<NB, BT, 0, stream>>>(flags, blk_cnt, out);
}